// Round 6
// baseline (156.132 us; speedup 1.0000x reference)
//
#include <hip/hip_runtime.h>

// out[b,o,ds] = sum_i x[b,i] * peso[o,i,ds] for i where mask[o,i]==1
// B=256, IN=1024, OUT=512, DS=128, ~10% of (o,i) kept (mask values exactly {0,1}).
//
// spmm v4: R1 dataflow, but x-slab loads moved from SMEM (s_load, out-of-order,
// lgkmcnt(0) full-drain kills prefetch) to VMEM (vmcnt, in-order, counted waits)
// via an opaque-VGPR byte offset. Depth-2 pipeline on both w and x.
// block=(o, 64-b tile), 4 waves; wave -> 16 b rows, lane -> float2 of ds.

#define B_   256
#define IN_  1024
#define OUT_ 512
#define DS_  128

// ws layout:
//   [0, 1 MiB)              xT  float[IN_][B_]
//   [1 MiB, +2 KiB)         cnt int[OUT_]
//   [1 MiB + 4 KiB, +2 MiB) idx int[OUT_][IN_]

__global__ __launch_bounds__(256) void transpose_x(const float* __restrict__ x,
                                                   float* __restrict__ xT) {
    __shared__ float tile[64][65];
    int t  = threadIdx.x;
    int c  = t & 63;
    int r0 = t >> 6;
    int i0 = (blockIdx.x & 15) * 64;
    int b0 = (blockIdx.x >> 4) * 64;
#pragma unroll
    for (int k = 0; k < 16; ++k) {
        int r = r0 + k * 4;
        tile[r][c] = x[(size_t)(b0 + r) * IN_ + i0 + c];
    }
    __syncthreads();
#pragma unroll
    for (int k = 0; k < 16; ++k) {
        int r = r0 + k * 4;
        xT[(size_t)(i0 + r) * B_ + b0 + c] = tile[c][r];
    }
}

__global__ __launch_bounds__(256) void build_idx(const float* __restrict__ mask,
                                                 int* __restrict__ cnt,
                                                 int* __restrict__ idx) {
    int o    = blockIdx.x;
    int t    = threadIdx.x;
    int lane = t & 63;
    int wv   = t >> 6;
    const float* mrow = mask + (size_t)o * IN_;

    int loc[4];
    int c = 0;
    int ibase = t * 4;
#pragma unroll
    for (int k = 0; k < 4; ++k) {
        if (mrow[ibase + k] != 0.0f) loc[c++] = ibase + k;
    }
    int v = c;
#pragma unroll
    for (int off = 1; off < 64; off <<= 1) {
        int u = __shfl_up(v, off, 64);
        if (lane >= off) v += u;
    }
    __shared__ int wsum[4];
    if (lane == 63) wsum[wv] = v;
    __syncthreads();
    int base = 0;
    for (int w = 0; w < wv; ++w) base += wsum[w];
    int excl = base + v - c;

    int* orow = idx + (size_t)o * IN_;
    for (int k = 0; k < c; ++k) orow[excl + k] = loc[k];
    if (t == 255) cnt[o] = base + v;
}

__global__ __launch_bounds__(256) void spmm_kernel(const float* __restrict__ xT,
                                                   const float* __restrict__ peso,
                                                   const int* __restrict__ cnt,
                                                   const int* __restrict__ idx,
                                                   float* __restrict__ out) {
    __shared__ int sidx[IN_];

    int bid  = blockIdx.x;
    int o    = bid & (OUT_ - 1);          // all 4 b-tiles of an o land on one XCD
    int bt   = bid >> 9;                  // 0..3
    int t    = threadIdx.x;
    int lane = t & 63;
    int wv   = __builtin_amdgcn_readfirstlane(t >> 6);
    int b0   = bt * 64 + wv * 16;         // this wave's 16 b rows

    int n = cnt[o];
    const int* irow = idx + (size_t)o * IN_;
    for (int f = t; f < n; f += 256) sidx[f] = irow[f];
    __syncthreads();

    float2 acc[16];
#pragma unroll
    for (int k = 0; k < 16; ++k) acc[k] = make_float2(0.0f, 0.0f);

    const float2* wlane = (const float2*)(peso + (size_t)o * IN_ * DS_) + lane;
    const char*   xbp   = (const char*)(xT + b0);

    // depth-2 software pipeline; x-slab via VMEM (opaque VGPR offset)
    int i_cur = (n > 0) ? __builtin_amdgcn_readfirstlane(sidx[0]) : 0;
    float2 w_cur = wlane[(size_t)i_cur * (DS_ / 2)];
    int bo = i_cur * (int)(B_ * sizeof(float));
    asm volatile("" : "+v"(bo));                       // force VMEM addressing
    const float4* xp = (const float4*)(xbp + bo);
    float4 xc0 = xp[0], xc1 = xp[1], xc2 = xp[2], xc3 = xp[3];

#pragma unroll 2
    for (int j = 0; j < n; ++j) {
        int jn = (j + 1 < n) ? j + 1 : j;
        int i_nxt = __builtin_amdgcn_readfirstlane(sidx[jn]);
        float2 w_nxt = wlane[(size_t)i_nxt * (DS_ / 2)];   // 512B/wave
        int bo2 = i_nxt * (int)(B_ * sizeof(float));
        asm volatile("" : "+v"(bo2));
        const float4* xq = (const float4*)(xbp + bo2);
        float4 xn0 = xq[0], xn1 = xq[1], xn2 = xq[2], xn3 = xq[3];

        float2 w = w_cur;
        acc[0].x  = fmaf(xc0.x, w.x, acc[0].x);  acc[0].y  = fmaf(xc0.x, w.y, acc[0].y);
        acc[1].x  = fmaf(xc0.y, w.x, acc[1].x);  acc[1].y  = fmaf(xc0.y, w.y, acc[1].y);
        acc[2].x  = fmaf(xc0.z, w.x, acc[2].x);  acc[2].y  = fmaf(xc0.z, w.y, acc[2].y);
        acc[3].x  = fmaf(xc0.w, w.x, acc[3].x);  acc[3].y  = fmaf(xc0.w, w.y, acc[3].y);
        acc[4].x  = fmaf(xc1.x, w.x, acc[4].x);  acc[4].y  = fmaf(xc1.x, w.y, acc[4].y);
        acc[5].x  = fmaf(xc1.y, w.x, acc[5].x);  acc[5].y  = fmaf(xc1.y, w.y, acc[5].y);
        acc[6].x  = fmaf(xc1.z, w.x, acc[6].x);  acc[6].y  = fmaf(xc1.z, w.y, acc[6].y);
        acc[7].x  = fmaf(xc1.w, w.x, acc[7].x);  acc[7].y  = fmaf(xc1.w, w.y, acc[7].y);
        acc[8].x  = fmaf(xc2.x, w.x, acc[8].x);  acc[8].y  = fmaf(xc2.x, w.y, acc[8].y);
        acc[9].x  = fmaf(xc2.y, w.x, acc[9].x);  acc[9].y  = fmaf(xc2.y, w.y, acc[9].y);
        acc[10].x = fmaf(xc2.z, w.x, acc[10].x); acc[10].y = fmaf(xc2.z, w.y, acc[10].y);
        acc[11].x = fmaf(xc2.w, w.x, acc[11].x); acc[11].y = fmaf(xc2.w, w.y, acc[11].y);
        acc[12].x = fmaf(xc3.x, w.x, acc[12].x); acc[12].y = fmaf(xc3.x, w.y, acc[12].y);
        acc[13].x = fmaf(xc3.y, w.x, acc[13].x); acc[13].y = fmaf(xc3.y, w.y, acc[13].y);
        acc[14].x = fmaf(xc3.z, w.x, acc[14].x); acc[14].y = fmaf(xc3.z, w.y, acc[14].y);
        acc[15].x = fmaf(xc3.w, w.x, acc[15].x); acc[15].y = fmaf(xc3.w, w.y, acc[15].y);

        w_cur = w_nxt;
        xc0 = xn0; xc1 = xn1; xc2 = xn2; xc3 = xn3;
    }

    float* obase = out + (size_t)b0 * (OUT_ * DS_) + o * DS_ + 2 * lane;
#pragma unroll
    for (int k = 0; k < 16; ++k) {
        *(float2*)(obase + (size_t)k * (OUT_ * DS_)) = acc[k];  // 512B/wave contiguous
    }
}

extern "C" void kernel_launch(void* const* d_in, const int* in_sizes, int n_in,
                              void* d_out, int out_size, void* d_ws, size_t ws_size,
                              hipStream_t stream) {
    const float* x    = (const float*)d_in[0];
    const float* peso = (const float*)d_in[1];
    const float* mask = (const float*)d_in[2];
    float* out = (float*)d_out;

    char* ws = (char*)d_ws;
    float* xT  = (float*)ws;
    int*   cnt = (int*)(ws + (1 << 20));
    int*   idx = (int*)(ws + (1 << 20) + 4096);

    transpose_x<<<64, 256, 0, stream>>>(x, xT);
    build_idx<<<OUT_, 256, 0, stream>>>(mask, cnt, idx);
    spmm_kernel<<<OUT_ * 4, 256, 0, stream>>>(xT, peso, cnt, idx, out);
}

// Round 7
// 32.976 us; speedup vs baseline: 4.7347x; 4.7347x over previous
//
#include <hip/hip_runtime.h>

// out[b,o,ds] = sum_i x[b,i] * peso[o,i,ds] for i where mask[o,i]==1
// B=256, IN=1024, OUT=512, DS=128, ~10% (o,i) kept; mask values exactly {0,1}.
//
// MFMA design: per o, out_o[256,128] = x[:,S_o] @ W_o[S_o,:] with compacted K.
// 2 blocks per o (128 b-rows each), 512 thr / 8 waves. Per 32-K step: stage
// x (bf16, pre-transposed) + w (f32->bf16) into LDS (pitch 80 B rows -> max
// 2-way bank conflicts), 8x mfma_f32_16x16x32_bf16 per wave (2x4 16x16 tiles).
// T14: next step's global loads issue before this step's MFMAs.

#define B_    256
#define IN_   1024
#define OUT_  512
#define DS_   128
#define PITCH 80   // bytes per LDS row (40 bf16); 5 mod 8 coprime -> conflict-free

typedef float  f32x4  __attribute__((ext_vector_type(4)));
typedef short  short8 __attribute__((ext_vector_type(8)));

static __device__ __forceinline__ unsigned short f2bf(float f) {
    unsigned u = __builtin_bit_cast(unsigned, f);
    u = u + 0x7fff + ((u >> 16) & 1);          // RNE
    return (unsigned short)(u >> 16);
}

// ws layout:
//   [0, 512 KiB)            xTbf ushort[IN_][B_]  (bf16)
//   [1 MiB, +2 KiB)         cnt  int[OUT_]
//   [1 MiB + 4 KiB, +2 MiB) idx  int[OUT_][IN_]

__global__ __launch_bounds__(256) void transpose_x(const float* __restrict__ x,
                                                   unsigned short* __restrict__ xTbf) {
    __shared__ float tile[64][65];
    int t  = threadIdx.x;
    int c  = t & 63;
    int r0 = t >> 6;
    int i0 = (blockIdx.x & 15) * 64;
    int b0 = (blockIdx.x >> 4) * 64;
#pragma unroll
    for (int k = 0; k < 16; ++k) {
        int r = r0 + k * 4;
        tile[r][c] = x[(size_t)(b0 + r) * IN_ + i0 + c];
    }
    __syncthreads();
#pragma unroll
    for (int k = 0; k < 16; ++k) {
        int r = r0 + k * 4;
        xTbf[(size_t)(i0 + r) * B_ + b0 + c] = f2bf(tile[c][r]);
    }
}

__global__ __launch_bounds__(256) void build_idx(const float* __restrict__ mask,
                                                 int* __restrict__ cnt,
                                                 int* __restrict__ idx) {
    int o    = blockIdx.x;
    int t    = threadIdx.x;
    int lane = t & 63;
    int wv   = t >> 6;
    const float* mrow = mask + (size_t)o * IN_;

    int loc[4];
    int c = 0;
    int ibase = t * 4;
#pragma unroll
    for (int k = 0; k < 4; ++k) {
        if (mrow[ibase + k] != 0.0f) loc[c++] = ibase + k;
    }
    int v = c;
#pragma unroll
    for (int off = 1; off < 64; off <<= 1) {
        int u = __shfl_up(v, off, 64);
        if (lane >= off) v += u;
    }
    __shared__ int wsum[4];
    if (lane == 63) wsum[wv] = v;
    __syncthreads();
    int base = 0;
    for (int w = 0; w < wv; ++w) base += wsum[w];
    int excl = base + v - c;

    int* orow = idx + (size_t)o * IN_;
    for (int k = 0; k < c; ++k) orow[excl + k] = loc[k];
    if (t == 255) cnt[o] = base + v;
}

__global__ __launch_bounds__(512, 4) void spmm_mfma(const unsigned short* __restrict__ xTbf,
                                                    const float* __restrict__ peso,
                                                    const int* __restrict__ cnt,
                                                    const int* __restrict__ idx,
                                                    float* __restrict__ out) {
    __shared__ int sidx[IN_];
    __shared__ uint4 xa4[128 * PITCH / 16];   // xa[b=0..127][k=0..31] bf16, pitch 80B
    __shared__ uint4 wt4[128 * PITCH / 16];   // wT[ds=0..127][k=0..31] bf16, pitch 80B
    char* xa = (char*)xa4;
    char* wt = (char*)wt4;

    int bid  = blockIdx.x;
    int c8   = bid & 7;                        // XCD id (round-robin dispatch)
    int m    = bid >> 3;
    int o    = (m >> 1) * 8 + c8;              // both halves of an o -> same XCD
    int half = m & 1;
    int t    = threadIdx.x;
    int lane = t & 63;
    int wv   = __builtin_amdgcn_readfirstlane(t >> 6);
    int wr   = wv & 3;                         // row group: 32 b-rows
    int wc   = wv >> 2;                        // col group: 64 ds-cols

    int n = cnt[o];
    const int* irow = idx + (size_t)o * IN_;
    for (int f = t; f < n; f += 512) sidx[f] = irow[f];

    f32x4 acc[2][4];
#pragma unroll
    for (int a = 0; a < 2; ++a)
#pragma unroll
        for (int b = 0; b < 4; ++b) acc[a][b] = (f32x4){0.f, 0.f, 0.f, 0.f};

    int sds = t & 127;                         // staging row (b or ds)
    int kg  = t >> 7;                          // k-chunk 0..3 (8 slots each)
    const float*          wrow = peso + (size_t)o * IN_ * DS_ + sds;
    const unsigned short* xrow = xTbf + half * 128 + sds;
    int st_off = sds * PITCH + kg * 16;
    int a_off  = (wr * 32 + (lane & 15)) * PITCH + (lane >> 4) * 16;
    int b_off  = (wc * 64 + (lane & 15)) * PITCH + (lane >> 4) * 16;

    __syncthreads();                           // sidx ready

    unsigned short xv[8];
    float          wf[8];

#define STAGE_LOAD(c0_)                                            \
    do {                                                           \
        _Pragma("unroll")                                          \
        for (int j = 0; j < 8; ++j) {                              \
            int kk  = (c0_) + kg * 8 + j;                          \
            int ok  = kk < n;                                      \
            int kks = ok ? kk : 0;                                 \
            int i   = sidx[kks];                                   \
            unsigned short xu = xrow[(size_t)i * B_];              \
            float          wl = wrow[(size_t)i * DS_];             \
            xv[j] = ok ? xu : (unsigned short)0;                   \
            wf[j] = ok ? wl : 0.0f;                                \
        }                                                          \
    } while (0)

    if (n > 0) STAGE_LOAD(0);

    for (int c0 = 0; c0 < n; c0 += 32) {
        __syncthreads();                       // prev compute done; LDS reusable
        uint4 xw, ww;
        xw.x = (unsigned)xv[0] | ((unsigned)xv[1] << 16);
        xw.y = (unsigned)xv[2] | ((unsigned)xv[3] << 16);
        xw.z = (unsigned)xv[4] | ((unsigned)xv[5] << 16);
        xw.w = (unsigned)xv[6] | ((unsigned)xv[7] << 16);
        ww.x = (unsigned)f2bf(wf[0]) | ((unsigned)f2bf(wf[1]) << 16);
        ww.y = (unsigned)f2bf(wf[2]) | ((unsigned)f2bf(wf[3]) << 16);
        ww.z = (unsigned)f2bf(wf[4]) | ((unsigned)f2bf(wf[5]) << 16);
        ww.w = (unsigned)f2bf(wf[6]) | ((unsigned)f2bf(wf[7]) << 16);
        *(uint4*)(xa + st_off) = xw;
        *(uint4*)(wt + st_off) = ww;
        __syncthreads();                       // tiles ready

        if (c0 + 32 < n) STAGE_LOAD(c0 + 32);  // issue next loads before MFMAs

        short8 afr[2], bfr[4];
#pragma unroll
        for (int rt = 0; rt < 2; ++rt)
            afr[rt] = *(const short8*)(xa + a_off + rt * 16 * PITCH);
#pragma unroll
        for (int ct = 0; ct < 4; ++ct)
            bfr[ct] = *(const short8*)(wt + b_off + ct * 16 * PITCH);
#pragma unroll
        for (int rt = 0; rt < 2; ++rt)
#pragma unroll
            for (int ct = 0; ct < 4; ++ct)
                acc[rt][ct] = __builtin_amdgcn_mfma_f32_16x16x32_bf16(
                    afr[rt], bfr[ct], acc[rt][ct], 0, 0, 0);
    }
#undef STAGE_LOAD

    // C/D layout (m89): col = lane&15, row = (lane>>4)*4 + q
    float* obase = out + (size_t)(half * 128 + wr * 32 + (lane >> 4) * 4) * (OUT_ * DS_)
                 + o * DS_ + wc * 64 + (lane & 15);
#pragma unroll
    for (int rt = 0; rt < 2; ++rt)
#pragma unroll
        for (int ct = 0; ct < 4; ++ct)
#pragma unroll
            for (int q = 0; q < 4; ++q)
                obase[(size_t)(rt * 16 + q) * (OUT_ * DS_) + ct * 16] = acc[rt][ct][q];
}

extern "C" void kernel_launch(void* const* d_in, const int* in_sizes, int n_in,
                              void* d_out, int out_size, void* d_ws, size_t ws_size,
                              hipStream_t stream) {
    const float* x    = (const float*)d_in[0];
    const float* peso = (const float*)d_in[1];
    const float* mask = (const float*)d_in[2];
    float* out = (float*)d_out;

    char* ws = (char*)d_ws;
    unsigned short* xTbf = (unsigned short*)ws;
    int*            cnt  = (int*)(ws + (1 << 20));
    int*            idx  = (int*)(ws + (1 << 20) + 4096);

    transpose_x<<<64, 256, 0, stream>>>(x, xTbf);
    build_idx<<<OUT_, 256, 0, stream>>>(mask, cnt, idx);
    spmm_mfma<<<OUT_ * 2, 512, 0, stream>>>(xTbf, peso, cnt, idx, out);
}